// Round 7
// baseline (101.033 us; speedup 1.0000x reference)
//
#include <hip/hip_runtime.h>
#include <hip/hip_bf16.h>
#include <stdint.h>

#define M_DIM 2048
#define K_DIM 4096
#define N_DIM 4096

typedef __attribute__((ext_vector_type(8))) short short8;
typedef __attribute__((ext_vector_type(4))) float f32x4;

#define MFMA __builtin_amdgcn_mfma_f32_16x16x32_bf16

// RNE float -> bf16, packed pair
__device__ __forceinline__ uint32_t bf16pk(float a, float b) {
  uint32_t ua = __float_as_uint(a);
  ua = (ua + 0x7FFFu + ((ua >> 16) & 1u)) >> 16;
  uint32_t ub = __float_as_uint(b);
  ub = (ub + 0x7FFFu + ((ub >> 16) & 1u)) >> 16;
  return ua | (ub << 16);
}

__device__ __forceinline__ void glds16(const char* g, char* l) {
  __builtin_amdgcn_global_load_lds((__attribute__((address_space(1))) void*)g,
                                   (__attribute__((address_space(3))) void*)l, 16, 0, 0);
}

// ---------------------------------------------------------------------------
// Image layout: BK=32 steps, 8KB tiles, [k8-slot 0..3][row 0..127][16B].
//  xImg[mt 0..15][step 0..127]  (16.78 MB): x[mt*128+row][step*32+slot*8+e]
//  wImg[nt 0..31][step 0..127]  (33.55 MB): W[step*32+slot*8+e][nt*128+col]
// Staging = verbatim linear copy; frag reads contiguous 256B per 16-lane
// group (R2/R4/R5-measured 0 bank conflicts). Index algebra re-verified R6.
// ---------------------------------------------------------------------------

// Prepass 1: grid 1024 = mt*64 + ktp (2 steps per block). 256 thr.
__global__ void __launch_bounds__(256) cvt_x_kernel(const float* __restrict__ x,
                                                    char* __restrict__ xImg) {
  const int mt = blockIdx.x >> 6, ktp = blockIdx.x & 63;
  const int tid = threadIdx.x;
  const int row = tid & 127, sh = tid >> 7;
  const int s = ktp * 2 + sh;
  const float* src = x + (size_t)(mt * 128 + row) * K_DIM + s * 32;
  char* dst = xImg + (size_t)(mt * 128 + s) * 8192 + row * 16;
#pragma unroll
  for (int slot = 0; slot < 4; ++slot) {
    float4 f0 = *(const float4*)(src + slot * 8);
    float4 f1 = *(const float4*)(src + slot * 8 + 4);
    uint4 pk;
    pk.x = bf16pk(f0.x, f0.y);
    pk.y = bf16pk(f0.z, f0.w);
    pk.z = bf16pk(f1.x, f1.y);
    pk.w = bf16pk(f1.z, f1.w);
    *(uint4*)(dst + slot * 2048) = pk;
  }
}

// Prepass 2: grid 2048 = nt*64 + ktp. 256 thr.
__global__ void __launch_bounds__(256) deq_w_kernel(const uint32_t* __restrict__ qweight,
                                                    const uint32_t* __restrict__ qzeros,
                                                    const float* __restrict__ scales,
                                                    char* __restrict__ wImg) {
  const int nt = blockIdx.x >> 6, ktp = blockIdx.x & 63;
  const int tid = threadIdx.x;
  const int n = tid & 127, sh = tid >> 7;
  const int s = ktp * 2 + sh;
  const int g = ktp >> 1;                      // group = 128 k = 4 steps
  const int gn = nt * 128 + n;
  uint32_t zq = qzeros[g * (N_DIM / 8) + (gn >> 3)];
  const int z = (int)((zq >> ((gn & 7) * 4)) & 15u) + 1;
  const float s_ = scales[g * N_DIM + gn];
  char* dst = wImg + (size_t)(nt * 128 + s) * 8192 + n * 16;
#pragma unroll
  for (int slot = 0; slot < 4; ++slot) {
    uint32_t q = qweight[(size_t)(s * 4 + slot) * N_DIM + gn];
    float f[8];
#pragma unroll
    for (int v = 0; v < 8; ++v) {
      int w = (int)((q >> (4 * v)) & 15u);
      f[v] = (float)(w - z) * s_;              // exact int sub, cvt, mul
    }
    uint4 pk;
    pk.x = bf16pk(f[0], f[1]);
    pk.y = bf16pk(f[2], f[3]);
    pk.z = bf16pk(f[4], f[5]);
    pk.w = bf16pk(f[6], f[7]);
    *(uint4*)(dst + slot * 2048) = pk;
  }
}

// ---------------------------------------------------------------------------
// GEMM: BM=BN=128, 2 waves/block (128 thr), per-wave 128x64, K-split 2.
// grid 1024 -> 4 INDEPENDENT blocks/CU (8 waves/CU): cross-block overlap
// fills per-block stall gaps (m114 mechanism). Ring-2 LDS x 16KB (32KB/blk).
//
// Per step t (RACE-FIXED schedule):
//   entry invariant: slot t&1 landed for ALL waves (own vmcnt(0) + barrier
//   at end of t-1); slot (t+1)&1's step-(t-1) reads retired (lgkmcnt(0)
//   before that same barrier).
//   1. STAGE(t+1) -> slot (t+1)&1   (8 glds, issued at top = max landing time)
//   2. 12 ds_reads from slot t&1
//   3. staggered lgkmcnt(3/2/1/0) + 4x8 MFMA (setprio-wrapped)
//   4. vmcnt(0)  <- own STAGE(t+1) landed  [BEFORE the barrier: race fix]
//   5. s_barrier -> globalizes: all waves' STAGE(t+1) landed.
// ---------------------------------------------------------------------------
__global__ void __launch_bounds__(128, 2) gemm_kernel(const char* __restrict__ xImg,
                                                      const char* __restrict__ wImg,
                                                      const float* __restrict__ bias,
                                                      float* __restrict__ out,
                                                      float* __restrict__ part1) {
  __shared__ uint4 ldsv[2048];                 // 32768 B = 2 slots x 16KB
  char* lds = (char*)ldsv;
  const int tid = threadIdx.x;
  const int lane = tid & 63, wc = tid >> 6;    // 2 waves split N
  const int lr = lane & 15, lk = lane >> 4;

  // XCD-chunked bijective swizzle (1024 % 8 == 0): per XCD one ks-half,
  // 8 B-panels (~4MB = L2) x all mb.
  const int bid = blockIdx.x;
  const int wg = (bid & 7) * 128 + (bid >> 3);
  const int mb = wg & 15, nb = (wg >> 4) & 31, ks = wg >> 9;

  f32x4 acc[8][4];
#pragma unroll
  for (int i = 0; i < 8; ++i)
#pragma unroll
    for (int j = 0; j < 4; ++j) acc[i][j] = f32x4{0.f, 0.f, 0.f, 0.f};

  const char* aT = xImg + (size_t)(mb * 128 + ks * 64) * 8192;
  const char* bT = wImg + (size_t)(nb * 128 + ks * 64) * 8192;

  int aoff[8], boff[4];
#pragma unroll
  for (int i = 0; i < 8; ++i) aoff[i] = lk * 2048 + (i * 16 + lr) * 16;
#pragma unroll
  for (int j = 0; j < 4; ++j) boff[j] = 8192 + lk * 2048 + (wc * 64 + j * 16 + lr) * 16;

#define STAGE(T, SB)                                                     \
  do {                                                                   \
    const char* sA = aT + (size_t)(T) * 8192;                            \
    const char* sB = bT + (size_t)(T) * 8192;                            \
    char* dA = lds + (SB);                                               \
    _Pragma("unroll")                                                    \
    for (int h = 0; h < 4; ++h) {                                        \
      glds16(sA + h * 2048 + tid * 16, dA + h * 2048 + tid * 16);        \
      glds16(sB + h * 2048 + tid * 16, dA + 8192 + h * 2048 + tid * 16); \
    }                                                                    \
  } while (0)

  // prologue: stage slot 0; own-wait BEFORE barrier (race-safe)
  STAGE(0, 0);
  asm volatile("s_waitcnt vmcnt(0)" ::: "memory");
  __builtin_amdgcn_sched_barrier(0);
  __builtin_amdgcn_s_barrier();

#pragma unroll 2
  for (int t = 0; t < 64; ++t) {
    const char* buf = lds + (t & 1) * 16384;
    if (t < 63) STAGE(t + 1, ((t + 1) & 1) * 16384);
    __builtin_amdgcn_sched_barrier(0);

    short8 a0 = *(const short8*)(buf + aoff[0]);
    short8 a1 = *(const short8*)(buf + aoff[1]);
    short8 a2 = *(const short8*)(buf + aoff[2]);
    short8 a3 = *(const short8*)(buf + aoff[3]);
    short8 a4 = *(const short8*)(buf + aoff[4]);
    short8 a5 = *(const short8*)(buf + aoff[5]);
    short8 a6 = *(const short8*)(buf + aoff[6]);
    short8 a7 = *(const short8*)(buf + aoff[7]);
    short8 b0 = *(const short8*)(buf + boff[0]);
    short8 b1 = *(const short8*)(buf + boff[1]);
    short8 b2 = *(const short8*)(buf + boff[2]);
    short8 b3 = *(const short8*)(buf + boff[3]);

    asm volatile("s_waitcnt lgkmcnt(3)" ::: "memory");
    __builtin_amdgcn_sched_barrier(0);
    __builtin_amdgcn_s_setprio(1);
    acc[0][0] = MFMA(a0, b0, acc[0][0], 0, 0, 0);
    acc[1][0] = MFMA(a1, b0, acc[1][0], 0, 0, 0);
    acc[2][0] = MFMA(a2, b0, acc[2][0], 0, 0, 0);
    acc[3][0] = MFMA(a3, b0, acc[3][0], 0, 0, 0);
    acc[4][0] = MFMA(a4, b0, acc[4][0], 0, 0, 0);
    acc[5][0] = MFMA(a5, b0, acc[5][0], 0, 0, 0);
    acc[6][0] = MFMA(a6, b0, acc[6][0], 0, 0, 0);
    acc[7][0] = MFMA(a7, b0, acc[7][0], 0, 0, 0);
    asm volatile("s_waitcnt lgkmcnt(2)" ::: "memory");
    __builtin_amdgcn_sched_barrier(0);
    acc[0][1] = MFMA(a0, b1, acc[0][1], 0, 0, 0);
    acc[1][1] = MFMA(a1, b1, acc[1][1], 0, 0, 0);
    acc[2][1] = MFMA(a2, b1, acc[2][1], 0, 0, 0);
    acc[3][1] = MFMA(a3, b1, acc[3][1], 0, 0, 0);
    acc[4][1] = MFMA(a4, b1, acc[4][1], 0, 0, 0);
    acc[5][1] = MFMA(a5, b1, acc[5][1], 0, 0, 0);
    acc[6][1] = MFMA(a6, b1, acc[6][1], 0, 0, 0);
    acc[7][1] = MFMA(a7, b1, acc[7][1], 0, 0, 0);
    asm volatile("s_waitcnt lgkmcnt(1)" ::: "memory");
    __builtin_amdgcn_sched_barrier(0);
    acc[0][2] = MFMA(a0, b2, acc[0][2], 0, 0, 0);
    acc[1][2] = MFMA(a1, b2, acc[1][2], 0, 0, 0);
    acc[2][2] = MFMA(a2, b2, acc[2][2], 0, 0, 0);
    acc[3][2] = MFMA(a3, b2, acc[3][2], 0, 0, 0);
    acc[4][2] = MFMA(a4, b2, acc[4][2], 0, 0, 0);
    acc[5][2] = MFMA(a5, b2, acc[5][2], 0, 0, 0);
    acc[6][2] = MFMA(a6, b2, acc[6][2], 0, 0, 0);
    acc[7][2] = MFMA(a7, b2, acc[7][2], 0, 0, 0);
    asm volatile("s_waitcnt lgkmcnt(0)" ::: "memory");
    __builtin_amdgcn_sched_barrier(0);
    acc[0][3] = MFMA(a0, b3, acc[0][3], 0, 0, 0);
    acc[1][3] = MFMA(a1, b3, acc[1][3], 0, 0, 0);
    acc[2][3] = MFMA(a2, b3, acc[2][3], 0, 0, 0);
    acc[3][3] = MFMA(a3, b3, acc[3][3], 0, 0, 0);
    acc[4][3] = MFMA(a4, b3, acc[4][3], 0, 0, 0);
    acc[5][3] = MFMA(a5, b3, acc[5][3], 0, 0, 0);
    acc[6][3] = MFMA(a6, b3, acc[6][3], 0, 0, 0);
    acc[7][3] = MFMA(a7, b3, acc[7][3], 0, 0, 0);
    __builtin_amdgcn_s_setprio(0);

    if (t < 63) {
      // RACE FIX: own STAGE(t+1) must land BEFORE the barrier, so that
      // after the barrier every wave's staged bytes are visible to all.
      asm volatile("s_waitcnt vmcnt(0)" ::: "memory");
      __builtin_amdgcn_sched_barrier(0);
      __builtin_amdgcn_s_barrier();
    }
  }
#undef STAGE

  // epilogue: C/D map col=lane&15, row=(lane>>4)*4+reg (verified R0-R5)
  const int colB = nb * 128 + wc * 64 + lr;
  const int rowB = mb * 128 + lk * 4;
  if (part1 != nullptr) {
    float* dst = ks ? part1 : out;
#pragma unroll
    for (int j = 0; j < 4; ++j) {
      int col = colB + j * 16;
      float bj = (ks == 0) ? bias[col] : 0.f;
#pragma unroll
      for (int i = 0; i < 8; ++i) {
        int row = rowB + i * 16;
#pragma unroll
        for (int r = 0; r < 4; ++r)
          dst[(size_t)(row + r) * N_DIM + col] = acc[i][j][r] + bj;
      }
    }
  } else {
#pragma unroll
    for (int j = 0; j < 4; ++j) {
      int col = colB + j * 16;
      float bj = (ks == 0) ? bias[col] : 0.f;
#pragma unroll
      for (int i = 0; i < 8; ++i) {
        int row = rowB + i * 16;
#pragma unroll
        for (int r = 0; r < 4; ++r)
          atomicAdd(&out[(size_t)(row + r) * N_DIM + col], acc[i][j][r] + bj);
      }
    }
  }
}

// out += part1
__global__ void __launch_bounds__(256) reduce_kernel(float* __restrict__ out,
                                                     const float* __restrict__ part1) {
  int i = blockIdx.x * 256 + threadIdx.x;
  float4 o = ((const float4*)out)[i];
  float4 p = ((const float4*)part1)[i];
  o.x += p.x; o.y += p.y; o.z += p.z; o.w += p.w;
  ((float4*)out)[i] = o;
}

// ---------------------------------------------------------------------------
// Fallback (workspace too small)
// ---------------------------------------------------------------------------
__global__ void fallback_kernel(const float* __restrict__ x, const uint32_t* __restrict__ qweight,
                                const uint32_t* __restrict__ qzeros, const float* __restrict__ scales,
                                const float* __restrict__ bias, float* __restrict__ out) {
  __shared__ float xs[16][17];
  __shared__ float ws[16][17];
  int tx = threadIdx.x, ty = threadIdx.y;
  int col = blockIdx.x * 16 + tx;
  int row = blockIdx.y * 16 + ty;
  float acc = 0.f;
  for (int k0 = 0; k0 < K_DIM; k0 += 16) {
    xs[ty][tx] = x[(size_t)row * K_DIM + k0 + tx];
    int k = k0 + ty;
    int g = k >> 7;
    uint32_t q = qweight[(size_t)(k >> 3) * N_DIM + col];
    int w = (int)((q >> ((k & 7) * 4)) & 15u);
    uint32_t zq = qzeros[g * (N_DIM / 8) + (col >> 3)];
    int z = (int)((zq >> ((col & 7) * 4)) & 15u) + 1;
    ws[ty][tx] = (float)(w - z) * scales[g * N_DIM + col];
    __syncthreads();
#pragma unroll
    for (int kk = 0; kk < 16; ++kk) acc += xs[ty][kk] * ws[kk][tx];
    __syncthreads();
  }
  out[(size_t)row * N_DIM + col] = acc + bias[col];
}

extern "C" void kernel_launch(void* const* d_in, const int* in_sizes, int n_in,
                              void* d_out, int out_size, void* d_ws, size_t ws_size,
                              hipStream_t stream) {
  const float* x = (const float*)d_in[0];
  const uint32_t* qweight = (const uint32_t*)d_in[1];
  const uint32_t* qzeros = (const uint32_t*)d_in[2];
  const float* scales = (const float*)d_in[3];
  // d_in[4] = g_idx (== arange(K)//128, folded into index math)
  const float* bias = (const float*)d_in[5];
  float* out = (float*)d_out;

  const size_t X_IMG = (size_t)16 * 128 * 8192;   // 16.78 MB
  const size_t W_IMG = (size_t)32 * 128 * 8192;   // 33.55 MB
  const size_t PART = (size_t)M_DIM * N_DIM * 4;  // 33.55 MB

  if (ws_size >= X_IMG + W_IMG + PART) {
    char* xImg = (char*)d_ws;
    char* wImg = (char*)d_ws + X_IMG;
    float* part1 = (float*)((char*)d_ws + X_IMG + W_IMG);
    cvt_x_kernel<<<1024, 256, 0, stream>>>(x, xImg);
    deq_w_kernel<<<2048, 256, 0, stream>>>(qweight, qzeros, scales, wImg);
    gemm_kernel<<<1024, 128, 0, stream>>>(xImg, wImg, bias, out, part1);
    reduce_kernel<<<8192, 256, 0, stream>>>(out, part1);
  } else if (ws_size >= X_IMG + W_IMG) {
    char* xImg = (char*)d_ws;
    char* wImg = (char*)d_ws + X_IMG;
    hipMemsetAsync(out, 0, (size_t)M_DIM * N_DIM * sizeof(float), stream);
    cvt_x_kernel<<<1024, 256, 0, stream>>>(x, xImg);
    deq_w_kernel<<<2048, 256, 0, stream>>>(qweight, qzeros, scales, wImg);
    gemm_kernel<<<1024, 128, 0, stream>>>(xImg, wImg, bias, out, nullptr);
  } else {
    fallback_kernel<<<dim3(N_DIM / 16, M_DIM / 16), dim3(16, 16), 0, stream>>>(
        x, qweight, qzeros, scales, bias, out);
  }
}

// Round 8
// 82.421 us; speedup vs baseline: 1.2258x; 1.2258x over previous
//
#include <hip/hip_runtime.h>
#include <hip/hip_bf16.h>
#include <stdint.h>

#define M_DIM 2048
#define K_DIM 4096
#define N_DIM 4096

typedef __attribute__((ext_vector_type(8))) short short8;
typedef __attribute__((ext_vector_type(4))) float f32x4;

#define MFMA __builtin_amdgcn_mfma_f32_16x16x32_bf16

// RNE float -> bf16, packed pair
__device__ __forceinline__ uint32_t bf16pk(float a, float b) {
  uint32_t ua = __float_as_uint(a);
  ua = (ua + 0x7FFFu + ((ua >> 16) & 1u)) >> 16;
  uint32_t ub = __float_as_uint(b);
  ub = (ub + 0x7FFFu + ((ub >> 16) & 1u)) >> 16;
  return ua | (ub << 16);
}

__device__ __forceinline__ void glds16(const char* g, char* l) {
  __builtin_amdgcn_global_load_lds((__attribute__((address_space(1))) void*)g,
                                   (__attribute__((address_space(3))) void*)l, 16, 0, 0);
}

// ---------------------------------------------------------------------------
// Image layout: BK=32 steps, 8KB tiles, [k8-slot 0..3][row 0..127][16B].
//  xImg[mt 0..15][step 0..127]  (16.78 MB): x[mt*128+row][step*32+slot*8+e]
//  wImg[nt 0..31][step 0..127]  (33.55 MB): W[step*32+slot*8+e][nt*128+col]
// Staging = verbatim linear copy; frag reads contiguous 256B per 16-lane
// group (R2-R7 measured 0 bank conflicts). Index algebra verified R6/R7.
// ---------------------------------------------------------------------------

// Merged prepass: grid 3072 x 256. bid<1024: cvt_x (R7-verified body);
// bid>=1024: deq_w (R7-verified body).
__global__ void __launch_bounds__(256) prep_kernel(const float* __restrict__ x,
                                                   const uint32_t* __restrict__ qweight,
                                                   const uint32_t* __restrict__ qzeros,
                                                   const float* __restrict__ scales,
                                                   char* __restrict__ xImg,
                                                   char* __restrict__ wImg) {
  const int tid = threadIdx.x;
  if (blockIdx.x < 1024) {
    const int bid = blockIdx.x;
    const int mt = bid >> 6, ktp = bid & 63;
    const int row = tid & 127, sh = tid >> 7;
    const int s = ktp * 2 + sh;
    const float* src = x + (size_t)(mt * 128 + row) * K_DIM + s * 32;
    char* dst = xImg + (size_t)(mt * 128 + s) * 8192 + row * 16;
#pragma unroll
    for (int slot = 0; slot < 4; ++slot) {
      float4 f0 = *(const float4*)(src + slot * 8);
      float4 f1 = *(const float4*)(src + slot * 8 + 4);
      uint4 pk;
      pk.x = bf16pk(f0.x, f0.y);
      pk.y = bf16pk(f0.z, f0.w);
      pk.z = bf16pk(f1.x, f1.y);
      pk.w = bf16pk(f1.z, f1.w);
      *(uint4*)(dst + slot * 2048) = pk;
    }
  } else {
    const int bid = blockIdx.x - 1024;
    const int nt = bid >> 6, ktp = bid & 63;
    const int n = tid & 127, sh = tid >> 7;
    const int s = ktp * 2 + sh;
    const int g = ktp >> 1;                    // group = 128 k = 4 steps
    const int gn = nt * 128 + n;
    uint32_t zq = qzeros[g * (N_DIM / 8) + (gn >> 3)];
    const int z = (int)((zq >> ((gn & 7) * 4)) & 15u) + 1;
    const float s_ = scales[g * N_DIM + gn];
    char* dst = wImg + (size_t)(nt * 128 + s) * 8192 + n * 16;
#pragma unroll
    for (int slot = 0; slot < 4; ++slot) {
      uint32_t q = qweight[(size_t)(s * 4 + slot) * N_DIM + gn];
      float f[8];
#pragma unroll
      for (int v = 0; v < 8; ++v) {
        int w = (int)((q >> (4 * v)) & 15u);
        f[v] = (float)(w - z) * s_;            // exact int sub, cvt, mul
      }
      uint4 pk;
      pk.x = bf16pk(f[0], f[1]);
      pk.y = bf16pk(f[2], f[3]);
      pk.z = bf16pk(f[4], f[5]);
      pk.w = bf16pk(f[6], f[7]);
      *(uint4*)(dst + slot * 2048) = pk;
    }
  }
}

// ---------------------------------------------------------------------------
// GEMM: BM=BN=128, 4 waves/block (256 thr) = 2 ks-halves x 2 N-halves,
// per-wave 128x64. IN-BLOCK K-split: wave pair ks handles K-steps
// ks*64..ks*64+63; partials meet in an LDS exchange epilogue (no part1,
// no reduce kernel, every out element written once).
// grid 512 -> 2 blocks/CU, 8 waves/CU (cross-block overlap per R7).
// Ring-2 LDS x 32KB/step-slot ([A0 8K][B0 8K][A1 8K][B1 8K]); 64KB/block.
//
// Per step t (R7's race-safe schedule, verbatim sync ordering):
//   1. STAGE(t+1): all 256 threads stage both halves' A+B (8 glds each)
//   2. 12 ds_reads from slot t&1 (wave's ks region)
//   3. staggered lgkmcnt(3/2/1/0) + 4x8 MFMA (setprio)
//   4. own vmcnt(0) BEFORE s_barrier (race fix, verified R7)
// Epilogue: __syncthreads; ks1 waves ds_write frags 0-3 at [0,32K),
// ks0 waves ds_write frags 4-7 at [32K,64K) (1KB-contiguous per instr,
// conflict-free); __syncthreads; each side reads partner frags, adds,
// stores its row-half with bias.
// ---------------------------------------------------------------------------
__global__ void __launch_bounds__(256, 2) gemm_kernel(const char* __restrict__ xImg,
                                                      const char* __restrict__ wImg,
                                                      const float* __restrict__ bias,
                                                      float* __restrict__ out) {
  __shared__ uint4 ldsv[4096];                 // 65536 B
  char* lds = (char*)ldsv;
  const int tid = threadIdx.x;
  const int lane = tid & 63, wid = tid >> 6;
  const int ks = wid >> 1, wc = wid & 1;       // ks-half, N-half
  const int lr = lane & 15, lk = lane >> 4;

  // XCD-chunked bijective swizzle (512 % 8 == 0): per XCD 4 B-panels
  // (~4MB = L2) x all mb.
  const int bid = blockIdx.x;
  const int wg = (bid & 7) * 64 + (bid >> 3);
  const int mb = wg & 15, nb = wg >> 4;        // mb 0..15, nb 0..31

  f32x4 acc[8][4];
#pragma unroll
  for (int i = 0; i < 8; ++i)
#pragma unroll
    for (int j = 0; j < 4; ++j) acc[i][j] = f32x4{0.f, 0.f, 0.f, 0.f};

  const char* aT0 = xImg + (size_t)mb * 128 * 8192;
  const char* bT0 = wImg + (size_t)nb * 128 * 8192;
  const char* aT1 = aT0 + (size_t)64 * 8192;   // ks=1 K-half
  const char* bT1 = bT0 + (size_t)64 * 8192;

  int aoff[8], boff[4];
#pragma unroll
  for (int i = 0; i < 8; ++i) aoff[i] = ks * 16384 + lk * 2048 + (i * 16 + lr) * 16;
#pragma unroll
  for (int j = 0; j < 4; ++j)
    boff[j] = ks * 16384 + 8192 + lk * 2048 + (wc * 64 + j * 16 + lr) * 16;

#define STAGE(T, SB)                                                     \
  do {                                                                   \
    char* d = lds + (SB);                                                \
    const char* sa0 = aT0 + (size_t)(T) * 8192;                          \
    const char* sb0 = bT0 + (size_t)(T) * 8192;                          \
    const char* sa1 = aT1 + (size_t)(T) * 8192;                          \
    const char* sb1 = bT1 + (size_t)(T) * 8192;                          \
    glds16(sa0 + tid * 16, d + tid * 16);                                \
    glds16(sa0 + 4096 + tid * 16, d + 4096 + tid * 16);                  \
    glds16(sb0 + tid * 16, d + 8192 + tid * 16);                         \
    glds16(sb0 + 4096 + tid * 16, d + 12288 + tid * 16);                 \
    glds16(sa1 + tid * 16, d + 16384 + tid * 16);                        \
    glds16(sa1 + 4096 + tid * 16, d + 20480 + tid * 16);                 \
    glds16(sb1 + tid * 16, d + 24576 + tid * 16);                        \
    glds16(sb1 + 4096 + tid * 16, d + 28672 + tid * 16);                 \
  } while (0)

  // prologue: stage slot 0; own-wait BEFORE barrier (race-safe, R7)
  STAGE(0, 0);
  asm volatile("s_waitcnt vmcnt(0)" ::: "memory");
  __builtin_amdgcn_sched_barrier(0);
  __builtin_amdgcn_s_barrier();

#pragma unroll 2
  for (int t = 0; t < 64; ++t) {
    const char* buf = lds + (t & 1) * 32768;
    if (t < 63) STAGE(t + 1, ((t + 1) & 1) * 32768);
    __builtin_amdgcn_sched_barrier(0);

    short8 a0 = *(const short8*)(buf + aoff[0]);
    short8 a1 = *(const short8*)(buf + aoff[1]);
    short8 a2 = *(const short8*)(buf + aoff[2]);
    short8 a3 = *(const short8*)(buf + aoff[3]);
    short8 a4 = *(const short8*)(buf + aoff[4]);
    short8 a5 = *(const short8*)(buf + aoff[5]);
    short8 a6 = *(const short8*)(buf + aoff[6]);
    short8 a7 = *(const short8*)(buf + aoff[7]);
    short8 b0 = *(const short8*)(buf + boff[0]);
    short8 b1 = *(const short8*)(buf + boff[1]);
    short8 b2 = *(const short8*)(buf + boff[2]);
    short8 b3 = *(const short8*)(buf + boff[3]);

    asm volatile("s_waitcnt lgkmcnt(3)" ::: "memory");
    __builtin_amdgcn_sched_barrier(0);
    __builtin_amdgcn_s_setprio(1);
    acc[0][0] = MFMA(a0, b0, acc[0][0], 0, 0, 0);
    acc[1][0] = MFMA(a1, b0, acc[1][0], 0, 0, 0);
    acc[2][0] = MFMA(a2, b0, acc[2][0], 0, 0, 0);
    acc[3][0] = MFMA(a3, b0, acc[3][0], 0, 0, 0);
    acc[4][0] = MFMA(a4, b0, acc[4][0], 0, 0, 0);
    acc[5][0] = MFMA(a5, b0, acc[5][0], 0, 0, 0);
    acc[6][0] = MFMA(a6, b0, acc[6][0], 0, 0, 0);
    acc[7][0] = MFMA(a7, b0, acc[7][0], 0, 0, 0);
    asm volatile("s_waitcnt lgkmcnt(2)" ::: "memory");
    __builtin_amdgcn_sched_barrier(0);
    acc[0][1] = MFMA(a0, b1, acc[0][1], 0, 0, 0);
    acc[1][1] = MFMA(a1, b1, acc[1][1], 0, 0, 0);
    acc[2][1] = MFMA(a2, b1, acc[2][1], 0, 0, 0);
    acc[3][1] = MFMA(a3, b1, acc[3][1], 0, 0, 0);
    acc[4][1] = MFMA(a4, b1, acc[4][1], 0, 0, 0);
    acc[5][1] = MFMA(a5, b1, acc[5][1], 0, 0, 0);
    acc[6][1] = MFMA(a6, b1, acc[6][1], 0, 0, 0);
    acc[7][1] = MFMA(a7, b1, acc[7][1], 0, 0, 0);
    asm volatile("s_waitcnt lgkmcnt(1)" ::: "memory");
    __builtin_amdgcn_sched_barrier(0);
    acc[0][2] = MFMA(a0, b2, acc[0][2], 0, 0, 0);
    acc[1][2] = MFMA(a1, b2, acc[1][2], 0, 0, 0);
    acc[2][2] = MFMA(a2, b2, acc[2][2], 0, 0, 0);
    acc[3][2] = MFMA(a3, b2, acc[3][2], 0, 0, 0);
    acc[4][2] = MFMA(a4, b2, acc[4][2], 0, 0, 0);
    acc[5][2] = MFMA(a5, b2, acc[5][2], 0, 0, 0);
    acc[6][2] = MFMA(a6, b2, acc[6][2], 0, 0, 0);
    acc[7][2] = MFMA(a7, b2, acc[7][2], 0, 0, 0);
    asm volatile("s_waitcnt lgkmcnt(0)" ::: "memory");
    __builtin_amdgcn_sched_barrier(0);
    acc[0][3] = MFMA(a0, b3, acc[0][3], 0, 0, 0);
    acc[1][3] = MFMA(a1, b3, acc[1][3], 0, 0, 0);
    acc[2][3] = MFMA(a2, b3, acc[2][3], 0, 0, 0);
    acc[3][3] = MFMA(a3, b3, acc[3][3], 0, 0, 0);
    acc[4][3] = MFMA(a4, b3, acc[4][3], 0, 0, 0);
    acc[5][3] = MFMA(a5, b3, acc[5][3], 0, 0, 0);
    acc[6][3] = MFMA(a6, b3, acc[6][3], 0, 0, 0);
    acc[7][3] = MFMA(a7, b3, acc[7][3], 0, 0, 0);
    __builtin_amdgcn_s_setprio(0);

    if (t < 63) {
      asm volatile("s_waitcnt vmcnt(0)" ::: "memory");   // own stage landed
      __builtin_amdgcn_sched_barrier(0);
      __builtin_amdgcn_s_barrier();                      // globalize
    }
  }
#undef STAGE

  // ---- epilogue: in-block cross-ks reduction via LDS exchange ----
  __syncthreads();   // all LDS reads of the K-loop done; ring space free
  if (ks == 1) {
#pragma unroll
    for (int i = 0; i < 4; ++i)
#pragma unroll
      for (int j = 0; j < 4; ++j)
        *(f32x4*)(lds + (wc * 16 + i * 4 + j) * 1024 + lane * 16) = acc[i][j];
  } else {
#pragma unroll
    for (int i = 4; i < 8; ++i)
#pragma unroll
      for (int j = 0; j < 4; ++j)
        *(f32x4*)(lds + 32768 + (wc * 16 + (i - 4) * 4 + j) * 1024 + lane * 16) = acc[i][j];
  }
  __syncthreads();

  // C/D map col=lane&15, row=(lane>>4)*4+reg (verified R0-R7)
  const int colB = nb * 128 + wc * 64 + lr;
  if (ks == 0) {
    // rows 0..63: own frags 0-3 + partner's (from [0,32K))
#pragma unroll
    for (int j = 0; j < 4; ++j) {
      int col = colB + j * 16;
      float bj = bias[col];
#pragma unroll
      for (int i = 0; i < 4; ++i) {
        f32x4 p = *(const f32x4*)(lds + (wc * 16 + i * 4 + j) * 1024 + lane * 16);
        int row = mb * 128 + i * 16 + lk * 4;
#pragma unroll
        for (int r = 0; r < 4; ++r)
          out[(size_t)(row + r) * N_DIM + col] = acc[i][j][r] + p[r] + bj;
      }
    }
  } else {
    // rows 64..127: own frags 4-7 + partner's (from [32K,64K))
#pragma unroll
    for (int j = 0; j < 4; ++j) {
      int col = colB + j * 16;
      float bj = bias[col];
#pragma unroll
      for (int i = 4; i < 8; ++i) {
        f32x4 p = *(const f32x4*)(lds + 32768 + (wc * 16 + (i - 4) * 4 + j) * 1024 + lane * 16);
        int row = mb * 128 + i * 16 + lk * 4;
#pragma unroll
        for (int r = 0; r < 4; ++r)
          out[(size_t)(row + r) * N_DIM + col] = acc[i][j][r] + p[r] + bj;
      }
    }
  }
}

// ---------------------------------------------------------------------------
// Fallback (workspace too small)
// ---------------------------------------------------------------------------
__global__ void fallback_kernel(const float* __restrict__ x, const uint32_t* __restrict__ qweight,
                                const uint32_t* __restrict__ qzeros, const float* __restrict__ scales,
                                const float* __restrict__ bias, float* __restrict__ out) {
  __shared__ float xs[16][17];
  __shared__ float ws[16][17];
  int tx = threadIdx.x, ty = threadIdx.y;
  int col = blockIdx.x * 16 + tx;
  int row = blockIdx.y * 16 + ty;
  float acc = 0.f;
  for (int k0 = 0; k0 < K_DIM; k0 += 16) {
    xs[ty][tx] = x[(size_t)row * K_DIM + k0 + tx];
    int k = k0 + ty;
    int g = k >> 7;
    uint32_t q = qweight[(size_t)(k >> 3) * N_DIM + col];
    int w = (int)((q >> ((k & 7) * 4)) & 15u);
    uint32_t zq = qzeros[g * (N_DIM / 8) + (col >> 3)];
    int z = (int)((zq >> ((col & 7) * 4)) & 15u) + 1;
    ws[ty][tx] = (float)(w - z) * scales[g * N_DIM + col];
    __syncthreads();
#pragma unroll
    for (int kk = 0; kk < 16; ++kk) acc += xs[ty][kk] * ws[kk][tx];
    __syncthreads();
  }
  out[(size_t)row * N_DIM + col] = acc + bias[col];
}

extern "C" void kernel_launch(void* const* d_in, const int* in_sizes, int n_in,
                              void* d_out, int out_size, void* d_ws, size_t ws_size,
                              hipStream_t stream) {
  const float* x = (const float*)d_in[0];
  const uint32_t* qweight = (const uint32_t*)d_in[1];
  const uint32_t* qzeros = (const uint32_t*)d_in[2];
  const float* scales = (const float*)d_in[3];
  // d_in[4] = g_idx (== arange(K)//128, folded into index math)
  const float* bias = (const float*)d_in[5];
  float* out = (float*)d_out;

  const size_t X_IMG = (size_t)16 * 128 * 8192;   // 16.78 MB
  const size_t W_IMG = (size_t)32 * 128 * 8192;   // 33.55 MB

  if (ws_size >= X_IMG + W_IMG) {
    char* xImg = (char*)d_ws;
    char* wImg = (char*)d_ws + X_IMG;
    prep_kernel<<<3072, 256, 0, stream>>>(x, qweight, qzeros, scales, xImg, wImg);
    gemm_kernel<<<512, 256, 0, stream>>>(xImg, wImg, bias, out);
  } else {
    fallback_kernel<<<dim3(N_DIM / 16, M_DIM / 16), dim3(16, 16), 0, stream>>>(
        x, qweight, qzeros, scales, bias, out);
  }
}